// Round 1
// baseline (93.485 us; speedup 1.0000x reference)
//
#include <hip/hip_runtime.h>
#include <hip/hip_bf16.h>

// Problem constants
#define K_DIM 4096
#define N_DIM 14336
#define M_DIM 256      // 8*32 rows
#define BN 64
#define BK 128         // == GROUP_SIZE -> one scale/zero group per K-iter
#define NITER 32       // K_DIM / BK
#define RS 136         // LDS row stride in bf16 elems (BK + 8 pad, keeps 16B align)

typedef __attribute__((ext_vector_type(4))) float f32x4;
typedef __attribute__((ext_vector_type(8))) short short8;

__device__ __forceinline__ unsigned short f2bf(float f) {
    union { float f; unsigned u; } v; v.f = f;
    unsigned r = v.u + 0x7fffu + ((v.u >> 16) & 1u);   // RNE
    return (unsigned short)(r >> 16);
}

// Pre-convert x (fp32 [256][4096]) into bf16 MFMA-A-fragment order:
// chunk = ktile*16 + mtile (ktile=k/32, mtile=m/16); within chunk, lane l
// holds 8 bf16 = x[mtile*16 + (l&15)][ktile*32 + (l>>4)*8 .. +8]
__global__ void convert_x_kernel(const float* __restrict__ x,
                                 unsigned short* __restrict__ xf) {
    int t = blockIdx.x * blockDim.x + threadIdx.x;   // 0..131071
    int chunk = t >> 6;
    int lane  = t & 63;
    int ktile = chunk >> 4;
    int mtile = chunk & 15;
    int m = mtile * 16 + (lane & 15);
    int k = ktile * 32 + ((lane >> 4) << 3);
    const float* xp = x + (size_t)m * K_DIM + k;
    float4 lo = *(const float4*)xp;
    float4 hi = *(const float4*)(xp + 4);
    union { unsigned short s[8]; int4 v; } o;
    o.s[0] = f2bf(lo.x); o.s[1] = f2bf(lo.y); o.s[2] = f2bf(lo.z); o.s[3] = f2bf(lo.w);
    o.s[4] = f2bf(hi.x); o.s[5] = f2bf(hi.y); o.s[6] = f2bf(hi.z); o.s[7] = f2bf(hi.w);
    *(int4*)(xf + ((size_t)t << 3)) = o.v;
}

// Main GEMM: grid = N/BN = 224 blocks, 512 threads = 8 waves (4M x 2N).
// Each block: full M=256 rows x BN=64 cols, K-loop of 32 iters (BK=128).
// w tile dequantized to bf16 in LDS [BN][RS], double-buffered.
template<bool USE_WS>
__global__ __launch_bounds__(512, 2)
void plq_gemm_kernel(const float* __restrict__ x,
                     const unsigned short* __restrict__ xf,
                     const int* __restrict__ q,
                     const float* __restrict__ qs,
                     const float* __restrict__ qb,
                     const float* __restrict__ bias,
                     float* __restrict__ out)
{
    __shared__ unsigned short wlds[2][BN * RS];

    const int tid  = threadIdx.x;
    const int lane = tid & 63;
    const int wv   = tid >> 6;   // wave 0..7
    const int wm   = wv >> 1;    // 0..3 : m-base = wm*64
    const int wn   = wv & 1;     // 0..1 : n-base = wn*32
    const int n0   = blockIdx.x * BN;

    // staging mapping: thread handles 8 consecutive k x 2 consecutive n
    const int tn = tid & 31;     // n_local = 2*tn
    const int tk = tid >> 5;     // k_local = 8*tk
    const int nl = tn * 2;
    const int kl = tk * 8;

    f32x4 acc[4][2] = {};

    int2   qr[8];
    float2 sv, zv;

    auto loadq = [&](int i) {
        const int* qp = q + (size_t)(i * BK + kl) * N_DIM + (n0 + nl);
        #pragma unroll
        for (int j = 0; j < 8; ++j)
            qr[j] = *(const int2*)(qp + (size_t)j * N_DIM);
        sv = *(const float2*)(qs + (size_t)i * N_DIM + (n0 + nl));
        zv = *(const float2*)(qb + (size_t)i * N_DIM + (n0 + nl));
    };

    auto deqw = [&](int b) {
        union { unsigned u[4]; int4 v; } p0, p1;
        #pragma unroll
        for (int j = 0; j < 4; ++j) {
            float a0 = (float)qr[2*j].x   * sv.x + zv.x;
            float a1 = (float)qr[2*j+1].x * sv.x + zv.x;
            float c0 = (float)qr[2*j].y   * sv.y + zv.y;
            float c1 = (float)qr[2*j+1].y * sv.y + zv.y;
            p0.u[j] = (unsigned)f2bf(a0) | ((unsigned)f2bf(a1) << 16);
            p1.u[j] = (unsigned)f2bf(c0) | ((unsigned)f2bf(c1) << 16);
        }
        *(int4*)&wlds[b][(nl + 0) * RS + kl] = p0.v;
        *(int4*)&wlds[b][(nl + 1) * RS + kl] = p1.v;
    };

    auto compute = [&](int i, int cur) {
        short8 afr[4][4];   // [ks][mf]
        if (USE_WS) {
            #pragma unroll
            for (int ks = 0; ks < 4; ++ks)
                #pragma unroll
                for (int mf = 0; mf < 4; ++mf) {
                    int chunk = (i * 4 + ks) * 16 + (wm * 4 + mf);
                    afr[ks][mf] = *(const short8*)(xf + ((size_t)chunk << 9) + (size_t)(lane << 3));
                }
        } else {
            #pragma unroll
            for (int ks = 0; ks < 4; ++ks)
                #pragma unroll
                for (int mf = 0; mf < 4; ++mf) {
                    int m = wm * 64 + mf * 16 + (lane & 15);
                    int k = i * BK + ks * 32 + ((lane >> 4) << 3);
                    const float* xp = x + (size_t)m * K_DIM + k;
                    float4 lo = *(const float4*)xp;
                    float4 hi = *(const float4*)(xp + 4);
                    union { unsigned short s[8]; short8 v; } u;
                    u.s[0] = f2bf(lo.x); u.s[1] = f2bf(lo.y); u.s[2] = f2bf(lo.z); u.s[3] = f2bf(lo.w);
                    u.s[4] = f2bf(hi.x); u.s[5] = f2bf(hi.y); u.s[6] = f2bf(hi.z); u.s[7] = f2bf(hi.w);
                    afr[ks][mf] = u.v;
                }
        }
        #pragma unroll
        for (int ks = 0; ks < 4; ++ks) {
            const int kb = ks * 32 + ((lane >> 4) << 3);
            short8 b0 = *(const short8*)&wlds[cur][(wn * 32 +      (lane & 15)) * RS + kb];
            short8 b1 = *(const short8*)&wlds[cur][(wn * 32 + 16 + (lane & 15)) * RS + kb];
            #pragma unroll
            for (int mf = 0; mf < 4; ++mf) {
                acc[mf][0] = __builtin_amdgcn_mfma_f32_16x16x32_bf16(afr[ks][mf], b0, acc[mf][0], 0, 0, 0);
                acc[mf][1] = __builtin_amdgcn_mfma_f32_16x16x32_bf16(afr[ks][mf], b1, acc[mf][1], 0, 0, 0);
            }
        }
    };

    loadq(0);
    deqw(0);
    __syncthreads();

    for (int i = 0; i < NITER; ++i) {
        const int cur = i & 1;
        if (i + 1 < NITER) loadq(i + 1);     // issue next-group HBM loads early
        compute(i, cur);                     // A from global(L2), B from LDS, 32 MFMA/wave
        if (i + 1 < NITER) deqw(cur ^ 1);    // dequant + write other buffer
        __syncthreads();
    }

    // epilogue: C/D layout col = lane&15, row = (lane>>4)*4 + r
    #pragma unroll
    for (int nf = 0; nf < 2; ++nf) {
        const int n = n0 + wn * 32 + nf * 16 + (lane & 15);
        const float bb = bias[n];
        #pragma unroll
        for (int mf = 0; mf < 4; ++mf) {
            const int m0 = wm * 64 + mf * 16 + ((lane >> 4) << 2);
            #pragma unroll
            for (int r = 0; r < 4; ++r)
                out[(size_t)(m0 + r) * N_DIM + n] = acc[mf][nf][r] + bb;
        }
    }
}

extern "C" void kernel_launch(void* const* d_in, const int* in_sizes, int n_in,
                              void* d_out, int out_size, void* d_ws, size_t ws_size,
                              hipStream_t stream) {
    const float* x    = (const float*)d_in[0];
    const int*   qk   = (const int*)d_in[1];
    const float* qs   = (const float*)d_in[2];
    const float* qb   = (const float*)d_in[3];
    const float* bias = (const float*)d_in[4];
    float* out = (float*)d_out;

    const size_t xf_bytes = (size_t)M_DIM * K_DIM * sizeof(unsigned short);
    if (ws_size >= xf_bytes) {
        unsigned short* xf = (unsigned short*)d_ws;
        convert_x_kernel<<<512, 256, 0, stream>>>(x, xf);
        plq_gemm_kernel<true><<<N_DIM / BN, 512, 0, stream>>>(x, xf, qk, qs, qb, bias, out);
    } else {
        plq_gemm_kernel<false><<<N_DIM / BN, 512, 0, stream>>>(x, nullptr, qk, qs, qb, bias, out);
    }
}